// Round 12
// baseline (174.298 us; speedup 1.0000x reference)
//
#include <hip/hip_runtime.h>

#define NN 200000
#define EE (NN - 1)
#define NSTEPS 4
#define DTC 0.01f
#define WPB 4
#define NPB 64            // nodes per block (1 tile of 16 per wave x 4 waves)
#define GRID 3125         // 200000/64 exact

typedef __attribute__((ext_vector_type(8))) _Float16 f16x8;
typedef __attribute__((ext_vector_type(2))) _Float16 f16x2;
typedef __attribute__((ext_vector_type(4))) float f32x4;

struct H4 { f16x2 a, b, c, d; };

__device__ __forceinline__ f16x2 c2h(float lo, float hi) {
    return __builtin_bit_cast(f16x2, __builtin_amdgcn_cvt_pkrtz(lo, hi)); // 1 instr
}
__device__ __forceinline__ unsigned pk2h(float lo, float hi) {
    return __builtin_bit_cast(unsigned, __builtin_amdgcn_cvt_pkrtz(lo, hi));
}
__device__ __forceinline__ f16x8 h8(f16x2 a, f16x2 b, f16x2 c, f16x2 d) {
    H4 t{a, b, c, d};
    return __builtin_bit_cast(f16x8, t);
}
__device__ __forceinline__ f16x2 relu2(f16x2 v) {   // v_pk_max_f16 vs 0
    f16x2 r;
    asm("v_pk_max_f16 %0, %1, 0" : "=v"(r) : "v"(v));
    return r;
}
__device__ __forceinline__ float swishf(float x) { return x / (1.0f + __expf(-x)); }

// dimension relabeling (verified R8+): C output (ct,q,r) packs directly into
// the next GEMM's B operand slots; B pos k <-> original dim permk(k).
__device__ __forceinline__ int permk(int k) {
    return (k & 0x23) | ((k & 4) << 2) | ((k & 0x18) >> 1);
}

// set dword 3 (f16 pair 3) of an f16x8 where cond holds: 1 v_cndmask
__device__ __forceinline__ f16x8 setw(f16x8 v, bool cond, unsigned nw) {
    uint4 u = __builtin_bit_cast(uint4, v);
    u.w = cond ? nw : u.w;
    return __builtin_bit_cast(f16x8, u);
}

// ws layout (ushort offsets within the weight region):
// [0,4096)      w1s   (W1ext^T, unscaled — used for U = W1·[Y,t0,1])
// [4096,8192)   w1h2  (W1ext^T * h/2 — hc at s=1,2)
// [8192,12288)  w1h   (W1ext^T * h   — hc at s=3)
// [12288,16384) w2s
// [16384,16896) encN ; [16896,17408) encE ; [17408,17920) dW1 ;
// [17920,18432) dW2 ; [18432,19456) outW
//
// All w1*/w2 arrays use the lane-linear swizzle (R22/R23-verified conflict-
// free): frag elem (od=ct*16+mm, k=kt*32+qq*8+jj) at ushort idx
// ct*1024 + kt*512 + (qq*16+mm)*8 + jj.
__global__ void gnode_weights(const float* __restrict__ ode_w1, const float* __restrict__ ode_b1,
                              const float* __restrict__ ode_w2, const float* __restrict__ ode_b2,
                              const float* __restrict__ enc_n_w2, const float* __restrict__ enc_e_w2,
                              const float* __restrict__ dec_n_w1, const float* __restrict__ dec_n_w2,
                              const float* __restrict__ node_out_w,
                              unsigned short* __restrict__ wg)
{
    const int b = blockIdx.x;
    const int tid = threadIdx.x;
    const float hh = 1.0f / NSTEPS;
    if (b < 8) {                     // W1ext^T / W2ext^T, permuted columns
        const int i = tid + b * 256;
        const int od = i >> 5;
        const int k2 = (i & 31) * 2;
        const int s0 = permk(k2);
        const int s1 = s0 + 1;
        float a0 = 0.f, a1 = 0.f, b0 = 0.f, b1 = 0.f;
        if (od < 50) {
            a0 = (s0 <= 50) ? ode_w1[s0 * 50 + od] : 0.f;
            a1 = (s1 <= 50) ? ode_w1[s1 * 50 + od]
                            : ((s1 == 51) ? ode_b1[od] : 0.f);
            b0 = (s0 < 50) ? ode_w2[s0 * 50 + od]
                           : ((s0 == 50) ? ode_b2[od] : 0.f);
            b1 = (s1 < 50) ? ode_w2[s1 * 50 + od] : 0.f;
        }
        // lane-linear swizzled destination (see comment above)
        const int ct = od >> 4;
        const int mm = od & 15;
        const int kt = k2 >> 5;
        const int qq = (k2 >> 3) & 3;
        const int jj = k2 & 7;
        const int didx = ct * 1024 + kt * 512 + (qq * 16 + mm) * 8 + jj;
        *(unsigned*)(wg + didx)         = pk2h(a0, a1);
        *(unsigned*)(wg + 4096 + didx)  = pk2h(a0 * (0.5f * hh), a1 * (0.5f * hh));
        *(unsigned*)(wg + 8192 + didx)  = pk2h(a0 * hh, a1 * hh);
        *(unsigned*)(wg + 12288 + didx) = pk2h(b0, b1);
    } else if (b < 10) {             // node_out_w^T 16x64, permuted cols
        const int i = tid + (b - 8) * 256;
        const int mm = i >> 5;
        const int kp = (i & 31) * 2;
        const int s0 = permk(kp);
        const float v0 = (s0     < 50) ? node_out_w[s0 * 16 + mm] : 0.f;
        const float v1 = (s0 + 1 < 50) ? node_out_w[(s0 + 1) * 16 + mm] : 0.f;
        *(unsigned*)(wg + 18432 + mm * 64 + kp) = pk2h(v0, v1);
    } else {                         // enc/dec 16x32 tiles, natural k (k>=16 zero)
        const int mm = tid >> 4;
        const int kp = (tid & 15) * 2;
        const bool rl = (kp < 16);
        const float eN0 = rl ? enc_n_w2[kp * 16 + mm] : 0.f;
        const float eN1 = rl ? enc_n_w2[(kp + 1) * 16 + mm] : 0.f;
        const float eE0 = rl ? enc_e_w2[kp * 16 + mm] : 0.f;
        const float eE1 = rl ? enc_e_w2[(kp + 1) * 16 + mm] : 0.f;
        const float d10 = rl ? dec_n_w1[kp * 16 + mm] : 0.f;
        const float d11 = rl ? dec_n_w1[(kp + 1) * 16 + mm] : 0.f;
        const float d20 = rl ? dec_n_w2[kp * 16 + mm] : 0.f;
        const float d21 = rl ? dec_n_w2[(kp + 1) * 16 + mm] : 0.f;
        *(unsigned*)(wg + 16384 + mm * 32 + kp) = pk2h(eN0, eN1);
        *(unsigned*)(wg + 16896 + mm * 32 + kp) = pk2h(eE0, eE1);
        *(unsigned*)(wg + 17408 + mm * 32 + kp) = pk2h(d10, d11);
        *(unsigned*)(wg + 17920 + mm * 32 + kp) = pk2h(d20, d21);
    }
}

// R28: R27 verbatim, launch_bounds (256,3)->(256,4). Ledger: measured
// occupancy tracks the LB register cap at ~0.7x ((256,2)->18%, (256,3)->
// 24-27% of 37.5% cap); LDS (37.9KB -> 4 blocks/CU = 50%) is NOT binding.
// R27's lean 1-tile body (VGPR=80 under a 170 budget, live set ~100-110)
// should fit the 128-reg 4-waves/SIMD budget. R19's (256,4) spill had 64
// pinned weight VGPRs + fat glue - both gone.
// Tripwire: WRITE_SIZE must stay ~5.47 MB; if it jumps, revert to (256,3).
__global__ __launch_bounds__(256, 4)
void gnode_main(const float* __restrict__ nodes,
                const float* __restrict__ edges,
                const float* __restrict__ g,
                const float* __restrict__ enc_n_w1, const float* __restrict__ enc_n_b1,
                const float* __restrict__ enc_n_b2,
                const float* __restrict__ enc_e_w1, const float* __restrict__ enc_e_b1,
                const float* __restrict__ enc_e_b2,
                const float* __restrict__ node_out_b,
                const float* __restrict__ dec_n_b1, const float* __restrict__ dec_n_b2,
                const float* __restrict__ dec_n_w3, const float* __restrict__ dec_n_b3,
                const unsigned short* __restrict__ wg,
                float* __restrict__ out, float* __restrict__ npos)
{
    __shared__ __attribute__((aligned(16))) unsigned short dscr[WPB][640];
    __shared__ __attribute__((aligned(16))) unsigned short sw[16384];  // 32 KB: w1s|w1h2|w1h|w2s

    const int tid  = threadIdx.x;
    const int lane = tid & 63;
    const int wave = __builtin_amdgcn_readfirstlane(tid >> 6);
    const int m = lane & 15;
    const int q = lane >> 4;
    const bool q0 = (q == 0);
    unsigned short* const dscrw = &dscr[wave][0];

    // stage the 4 weight arrays global->LDS (linear memcpy; pre-swizzled)
#pragma unroll
    for (int i = 0; i < 8; ++i)
        ((uint4*)sw)[tid + 256 * i] = ((const uint4*)wg)[tid + 256 * i];

    const int nd = blockIdx.x * NPB + wave * 16 + m;
    const int nc = (nd < NN) ? nd : (NN - 1);

    // zero decoder-scratch k=16..31 (dw1/dw2 A-rows are zero there, but LDS
    // garbage could be NaN; 0 * NaN != 0)
    *(uint2*)(dscrw + m * 40 + 16 + q * 4) = make_uint2(0u, 0u);

    const f32x4 zero4 = {0.f, 0.f, 0.f, 0.f};
    const f16x2 h2z = {(_Float16)0.f, (_Float16)0.f};
    const f16x8 z8 = h8(h2z, h2z, h2z, h2z);

    // state: Y/ACC/KC f16x8 (2 each, B layout); U f32 (4 f32x4, D layout).
    f16x8 Y[2], ACC[2], KC[2];
    f32x4 U[4];

    // ---------------- encoder (3 f16 MFMAs) ----------------
    {
        const f16x8 wNf = *(const f16x8*)(const void*)(wg + 16384 + m * 32 + q * 8);
        const f16x8 wEf = *(const f16x8*)(const void*)(wg + 16896 + m * 32 + q * 8);
        f32x4 bN, bE;
#pragma unroll
        for (int r = 0; r < 4; ++r) { bN[r] = enc_n_b2[q * 4 + r]; bE[r] = enc_e_b2[q * 4 + r]; }
        const float g0v = g[0], g1v = g[1];

        const int node = nc;
        f32x4 e0, e1, e2;
        {
            float nf[5];
#pragma unroll
            for (int c = 0; c < 5; ++c) nf[c] = nodes[node * 5 + c];
            f16x8 bfr = z8;
            if (q < 2) {
                float hv[8];
#pragma unroll
                for (int j = 0; j < 8; ++j) {
                    const int d = q * 8 + j;
                    float s = enc_n_b1[d];
#pragma unroll
                    for (int c = 0; c < 5; ++c) s = fmaf(nf[c], enc_n_w1[c * 16 + d], s);
                    hv[j] = swishf(s);
                }
                bfr = h8(c2h(hv[0], hv[1]), c2h(hv[2], hv[3]),
                         c2h(hv[4], hv[5]), c2h(hv[6], hv[7]));
            }
            e0 = __builtin_amdgcn_mfma_f32_16x16x32_f16(wNf, bfr, bN, 0, 0, 0);
        }
        {
            const float ev = (node < EE) ? edges[node] : 0.0f;
            f16x8 bfr = z8;
            if (q < 2) {
                float hv[8];
#pragma unroll
                for (int j = 0; j < 8; ++j) {
                    const int d = q * 8 + j;
                    hv[j] = swishf(fmaf(ev, enc_e_w1[d], enc_e_b1[d]));
                }
                bfr = h8(c2h(hv[0], hv[1]), c2h(hv[2], hv[3]),
                         c2h(hv[4], hv[5]), c2h(hv[6], hv[7]));
            }
            e1 = __builtin_amdgcn_mfma_f32_16x16x32_f16(wEf, bfr, bE, 0, 0, 0);
            if (node == NN - 1) e1 = zero4;
        }
        {
            const float ev = (node > 0) ? edges[node - 1] : 0.0f;
            f16x8 bfr = z8;
            if (q < 2) {
                float hv[8];
#pragma unroll
                for (int j = 0; j < 8; ++j) {
                    const int d = q * 8 + j;
                    hv[j] = swishf(fmaf(ev, enc_e_w1[d], enc_e_b1[d]));
                }
                bfr = h8(c2h(hv[0], hv[1]), c2h(hv[2], hv[3]),
                         c2h(hv[4], hv[5]), c2h(hv[6], hv[7]));
            }
            e2 = __builtin_amdgcn_mfma_f32_16x16x32_f16(wEf, bfr, bE, 0, 0, 0);
            if (node == 0) e2 = zero4;
        }
        Y[0] = h8(c2h(e0[0], e0[1]), c2h(e0[2], e0[3]),
                  c2h(e1[0], e1[1]), c2h(e1[2], e1[3]));
        Y[1] = h8(c2h(e2[0], e2[1]), c2h(e2[2], e2[3]),
                  q0 ? c2h(g0v, g1v) : h2z, h2z);
    }

    __syncthreads();    // sw ready before RK4

    // per-lane LDS fragment base: lane (m,q) -> slot q*16+m (lane-linear:
    // wave's b128 read covers 1024 contiguous bytes -> conflict-free)
    const unsigned short* const swl = sw + (q * 16 + m) * 8;

    // ---------------- RK4 (4 steps x 4 fully-unrolled stages) ----------
    const float hh = 1.0f / NSTEPS;
    float t0 = 0.0f;
    const unsigned inj1 = 0x00003C00u;   // f16 (1.0, 0.0): Δt/cb ≡ 1, bias from U

#pragma clang loop unroll(disable)
    for (int step = 0; step < NSTEPS; ++step) {
#pragma unroll
        for (int s = 0; s < 4; ++s) {
            f32x4 hc[4];
            if (s == 0) {
                // U = W1ext · [Y, t0, 1]  (once per RK4 step; hc(0) = U)
                const f16x8 y1x = setw(Y[1], q0, pk2h(t0, 1.0f));
#pragma unroll
                for (int ct = 0; ct < 4; ++ct) {
                    const f16x8 wa = *(const f16x8*)(const void*)(swl + ct * 1024);
                    const f16x8 wb = *(const f16x8*)(const void*)(swl + ct * 1024 + 512);
                    f32x4 c0 = __builtin_amdgcn_mfma_f32_16x16x32_f16(wa, Y[0], zero4, 0, 0, 0);
                    U[ct] = __builtin_amdgcn_mfma_f32_16x16x32_f16(wb, y1x, c0, 0, 0, 0);
                    hc[ct] = U[ct];
                }
            } else {
                // hc(s) = U + (cb_{s-1}·W1)·KC(s-1); cb=h/2 for s=1,2; cb=h for s=3
                const int cboff = (s == 3) ? 8192 : 4096;
#pragma unroll
                for (int ct = 0; ct < 4; ++ct) {
                    const f16x8 wa = *(const f16x8*)(const void*)(swl + cboff + ct * 1024);
                    const f16x8 wb = *(const f16x8*)(const void*)(swl + cboff + ct * 1024 + 512);
                    f32x4 c0 = __builtin_amdgcn_mfma_f32_16x16x32_f16(wa, KC[0], U[ct], 0, 0, 0);
                    hc[ct] = __builtin_amdgcn_mfma_f32_16x16x32_f16(wb, KC[1], c0, 0, 0, 0);
                }
            }

            f16x8 H[2];
            H[0] = h8(relu2(c2h(hc[0][0], hc[0][1])),
                      relu2(c2h(hc[0][2], hc[0][3])),
                      relu2(c2h(hc[1][0], hc[1][1])),
                      relu2(c2h(hc[1][2], hc[1][3])));
            f16x8 h1 = h8(relu2(c2h(hc[2][0], hc[2][1])),
                          relu2(c2h(hc[2][2], hc[2][3])),
                          relu2(c2h(hc[3][0], hc[3][1])),
                          relu2(c2h(hc[3][2], hc[3][3])));
            H[1] = setw(h1, q0, 0x3C003C00u);   // hidden bias slot (dim 50) = 1

            f32x4 kc[4];
#pragma unroll
            for (int ct = 0; ct < 4; ++ct) {
                const f16x8 wa = *(const f16x8*)(const void*)(swl + 12288 + ct * 1024);
                const f16x8 wb = *(const f16x8*)(const void*)(swl + 12288 + ct * 1024 + 512);
                f32x4 c0 = __builtin_amdgcn_mfma_f32_16x16x32_f16(wa, H[0], zero4, 0, 0, 0);
                kc[ct] = __builtin_amdgcn_mfma_f32_16x16x32_f16(wb, H[1], c0, 0, 0, 0);
            }

            const float ca = (s == 0 || s == 3) ? hh / 6.0f : hh / 3.0f;
            const f16x2 cah = c2h(ca, ca);
            const f16x8 ca8 = h8(cah, cah, cah, cah);

            KC[0] = h8(c2h(kc[0][0], kc[0][1]), c2h(kc[0][2], kc[0][3]),
                       c2h(kc[1][0], kc[1][1]), c2h(kc[1][2], kc[1][3]));
            KC[1] = h8(c2h(kc[2][0], kc[2][1]), c2h(kc[2][2], kc[2][3]),
                       c2h(kc[3][0], kc[3][1]), c2h(kc[3][2], kc[3][3]));
            if (s == 0) {
                ACC[0] = ca8 * KC[0] + Y[0];
                ACC[1] = ca8 * KC[1] + Y[1];
            } else {
                ACC[0] = ca8 * KC[0] + ACC[0];
                ACC[1] = ca8 * KC[1] + ACC[1];
            }
            if (s < 3) {
                KC[1] = setw(KC[1], q0, inj1);   // Δt/cb = 1 into slot 38
            } else {
                Y[0] = ACC[0];
                Y[1] = ACC[1];
            }
        }
        t0 += hh;
    }

    // ------------- decoder (4 f16 MFMAs; weights loaded HERE) -------
    const f16x8 dw1 = *(const f16x8*)(const void*)(wg + 17408 + m * 32 + q * 8);
    const f16x8 dw2 = *(const f16x8*)(const void*)(wg + 17920 + m * 32 + q * 8);
    const f16x8 ow0 = *(const f16x8*)(const void*)(wg + 18432 + m * 64 + q * 8);
    const f16x8 ow1 = *(const f16x8*)(const void*)(wg + 18432 + m * 64 + 32 + q * 8);
    f32x4 bO, bD1, bD2;
    float w3v[4];
#pragma unroll
    for (int r = 0; r < 4; ++r) {
        bO[r]  = node_out_b[q * 4 + r];
        bD1[r] = dec_n_b1[q * 4 + r];
        bD2[r] = dec_n_b2[q * 4 + r];
        w3v[r] = dec_n_w3[q * 4 + r];
    }

    {
        f32x4 nl2 = __builtin_amdgcn_mfma_f32_16x16x32_f16(ow0, Y[0], bO, 0, 0, 0);
        nl2       = __builtin_amdgcn_mfma_f32_16x16x32_f16(ow1, Y[1], nl2, 0, 0, 0);

        *(uint2*)(dscrw + m * 40 + q * 4) =
            make_uint2(pk2h(nl2[0], nl2[1]), pk2h(nl2[2], nl2[3]));
        f16x8 nB = *(const f16x8*)(const void*)(dscrw + m * 40 + q * 8);
        f32x4 dh = __builtin_amdgcn_mfma_f32_16x16x32_f16(dw1, nB, bD1, 0, 0, 0);
#pragma unroll
        for (int r = 0; r < 4; ++r) dh[r] = swishf(dh[r]);

        *(uint2*)(dscrw + m * 40 + q * 4) =
            make_uint2(pk2h(dh[0], dh[1]), pk2h(dh[2], dh[3]));
        f16x8 dB = *(const f16x8*)(const void*)(dscrw + m * 40 + q * 8);
        f32x4 dh2 = __builtin_amdgcn_mfma_f32_16x16x32_f16(dw2, dB, bD2, 0, 0, 0);
#pragma unroll
        for (int r = 0; r < 4; ++r) dh2[r] = swishf(dh2[r]);

        float p = dh2[0] * w3v[0];
        p = fmaf(dh2[1], w3v[1], p);
        p = fmaf(dh2[2], w3v[2], p);
        p = fmaf(dh2[3], w3v[3], p);
        p += __shfl_xor(p, 16);
        p += __shfl_xor(p, 32);
        p += dec_n_b3[0];

        const int node = nd;
        if (q0 && node < NN) {
            const float cur_pos = nodes[node * 5 + 0];
            const float c2 = nodes[node * 5 + 2];
            const float c3 = nodes[node * 5 + 3];
            const float cur_vel = nodes[node * 5 + 4];
            const float next_vel = fmaf(p, DTC, cur_vel);
            const float next_pos = fmaf(next_vel, DTC, cur_pos);
            out[node * 6 + 0] = next_pos;
            out[node * 6 + 1] = c2;
            out[node * 6 + 2] = c3;
            out[node * 6 + 3] = cur_vel;
            out[node * 6 + 4] = next_vel;
            out[node * 6 + 5] = p;
            npos[node] = next_pos;
        }
    }
}

// third pass: next_edges = diff(next_pos) from packed npos (coalesced), g_new
__global__ void gnode_edges(const float* __restrict__ npos,
                            float* __restrict__ out,
                            const float* __restrict__ g)
{
    const int e = blockIdx.x * blockDim.x + threadIdx.x;
    if (e < EE) {
        out[NN * 6 + e] = npos[e + 1] - npos[e];
    }
    if (e == 0) {
        out[NN * 6 + EE]     = g[0] + 1.0f;
        out[NN * 6 + EE + 1] = g[1];
    }
}

extern "C" void kernel_launch(void* const* d_in, const int* in_sizes, int n_in,
                              void* d_out, int out_size, void* d_ws, size_t ws_size,
                              hipStream_t stream) {
    const float* nodes      = (const float*)d_in[0];
    const float* edges      = (const float*)d_in[1];
    const float* g          = (const float*)d_in[2];
    const float* enc_n_w1   = (const float*)d_in[3];
    const float* enc_n_b1   = (const float*)d_in[4];
    const float* enc_n_w2   = (const float*)d_in[5];
    const float* enc_n_b2   = (const float*)d_in[6];
    const float* enc_e_w1   = (const float*)d_in[7];
    const float* enc_e_b1   = (const float*)d_in[8];
    const float* enc_e_w2   = (const float*)d_in[9];
    const float* enc_e_b2   = (const float*)d_in[10];
    const float* ode_w1     = (const float*)d_in[11];
    const float* ode_b1     = (const float*)d_in[12];
    const float* ode_w2     = (const float*)d_in[13];
    const float* ode_b2     = (const float*)d_in[14];
    const float* node_out_w = (const float*)d_in[15];
    const float* node_out_b = (const float*)d_in[16];
    const float* dec_n_w1   = (const float*)d_in[17];
    const float* dec_n_b1   = (const float*)d_in[18];
    const float* dec_n_w2   = (const float*)d_in[19];
    const float* dec_n_b2   = (const float*)d_in[20];
    const float* dec_n_w3   = (const float*)d_in[21];
    const float* dec_n_b3   = (const float*)d_in[22];
    float* out  = (float*)d_out;
    float* npos = (float*)d_ws;                               // NN floats
    unsigned short* wg = (unsigned short*)((char*)d_ws + (size_t)NN * 4);  // 38 KB

    gnode_weights<<<11, 256, 0, stream>>>(
        ode_w1, ode_b1, ode_w2, ode_b2,
        enc_n_w2, enc_e_w2, dec_n_w1, dec_n_w2, node_out_w, wg);

    gnode_main<<<GRID, 256, 0, stream>>>(
        nodes, edges, g,
        enc_n_w1, enc_n_b1, enc_n_b2,
        enc_e_w1, enc_e_b1, enc_e_b2,
        node_out_b, dec_n_b1, dec_n_b2, dec_n_w3, dec_n_b3,
        wg, out, npos);

    gnode_edges<<<(EE + 255) / 256, 256, 0, stream>>>(npos, out, g);
}

// Round 13
// 160.653 us; speedup vs baseline: 1.0849x; 1.0849x over previous
//
#include <hip/hip_runtime.h>

#define NN 200000
#define EE (NN - 1)
#define NSTEPS 4
#define DTC 0.01f
#define WPB 4
#define NPB 64            // nodes per block (1 tile of 16 per wave x 4 waves)
#define GRID 3125         // 200000/64 exact

typedef __attribute__((ext_vector_type(8))) _Float16 f16x8;
typedef __attribute__((ext_vector_type(2))) _Float16 f16x2;
typedef __attribute__((ext_vector_type(4))) float f32x4;

struct H4 { f16x2 a, b, c, d; };

__device__ __forceinline__ f16x2 c2h(float lo, float hi) {
    return __builtin_bit_cast(f16x2, __builtin_amdgcn_cvt_pkrtz(lo, hi)); // 1 instr
}
__device__ __forceinline__ unsigned pk2h(float lo, float hi) {
    return __builtin_bit_cast(unsigned, __builtin_amdgcn_cvt_pkrtz(lo, hi));
}
__device__ __forceinline__ f16x8 h8(f16x2 a, f16x2 b, f16x2 c, f16x2 d) {
    H4 t{a, b, c, d};
    return __builtin_bit_cast(f16x8, t);
}
__device__ __forceinline__ f16x2 relu2(f16x2 v) {   // v_pk_max_f16 vs 0
    f16x2 r;
    asm("v_pk_max_f16 %0, %1, 0" : "=v"(r) : "v"(v));
    return r;
}
__device__ __forceinline__ float swishf(float x) { return x / (1.0f + __expf(-x)); }

// dimension relabeling (verified R8+): C output (ct,q,r) packs directly into
// the next GEMM's B operand slots; B pos k <-> original dim permk(k).
__device__ __forceinline__ int permk(int k) {
    return (k & 0x23) | ((k & 4) << 2) | ((k & 0x18) >> 1);
}

// set dword 3 (f16 pair 3) of an f16x8 where cond holds: 1 v_cndmask
__device__ __forceinline__ f16x8 setw(f16x8 v, bool cond, unsigned nw) {
    uint4 u = __builtin_bit_cast(uint4, v);
    u.w = cond ? nw : u.w;
    return __builtin_bit_cast(f16x8, u);
}

// ws layout (ushort offsets within the weight region):
// [0,4096)      w1s   (W1ext^T, unscaled — used for U = W1·[Y,t0,1])
// [4096,8192)   w1h2  (W1ext^T * h/2 — hc at s=1,2)
// [8192,12288)  w1h   (W1ext^T * h   — hc at s=3)
// [12288,16384) w2s   (read into REGISTERS by gnode_main; not staged to LDS)
// [16384,16896) encN ; [16896,17408) encE ; [17408,17920) dW1 ;
// [17920,18432) dW2 ; [18432,19456) outW
//
// All w1*/w2 arrays use the lane-linear swizzle (R22/R23-verified conflict-
// free): frag elem (od=ct*16+mm, k=kt*32+qq*8+jj) at ushort idx
// ct*1024 + kt*512 + (qq*16+mm)*8 + jj  (slot index == lane id).
__global__ void gnode_weights(const float* __restrict__ ode_w1, const float* __restrict__ ode_b1,
                              const float* __restrict__ ode_w2, const float* __restrict__ ode_b2,
                              const float* __restrict__ enc_n_w2, const float* __restrict__ enc_e_w2,
                              const float* __restrict__ dec_n_w1, const float* __restrict__ dec_n_w2,
                              const float* __restrict__ node_out_w,
                              unsigned short* __restrict__ wg)
{
    const int b = blockIdx.x;
    const int tid = threadIdx.x;
    const float hh = 1.0f / NSTEPS;
    if (b < 8) {                     // W1ext^T / W2ext^T, permuted columns
        const int i = tid + b * 256;
        const int od = i >> 5;
        const int k2 = (i & 31) * 2;
        const int s0 = permk(k2);
        const int s1 = s0 + 1;
        float a0 = 0.f, a1 = 0.f, b0 = 0.f, b1 = 0.f;
        if (od < 50) {
            a0 = (s0 <= 50) ? ode_w1[s0 * 50 + od] : 0.f;
            a1 = (s1 <= 50) ? ode_w1[s1 * 50 + od]
                            : ((s1 == 51) ? ode_b1[od] : 0.f);
            b0 = (s0 < 50) ? ode_w2[s0 * 50 + od]
                           : ((s0 == 50) ? ode_b2[od] : 0.f);
            b1 = (s1 < 50) ? ode_w2[s1 * 50 + od] : 0.f;
        }
        // lane-linear swizzled destination (see comment above)
        const int ct = od >> 4;
        const int mm = od & 15;
        const int kt = k2 >> 5;
        const int qq = (k2 >> 3) & 3;
        const int jj = k2 & 7;
        const int didx = ct * 1024 + kt * 512 + (qq * 16 + mm) * 8 + jj;
        *(unsigned*)(wg + didx)         = pk2h(a0, a1);
        *(unsigned*)(wg + 4096 + didx)  = pk2h(a0 * (0.5f * hh), a1 * (0.5f * hh));
        *(unsigned*)(wg + 8192 + didx)  = pk2h(a0 * hh, a1 * hh);
        *(unsigned*)(wg + 12288 + didx) = pk2h(b0, b1);
    } else if (b < 10) {             // node_out_w^T 16x64, permuted cols
        const int i = tid + (b - 8) * 256;
        const int mm = i >> 5;
        const int kp = (i & 31) * 2;
        const int s0 = permk(kp);
        const float v0 = (s0     < 50) ? node_out_w[s0 * 16 + mm] : 0.f;
        const float v1 = (s0 + 1 < 50) ? node_out_w[(s0 + 1) * 16 + mm] : 0.f;
        *(unsigned*)(wg + 18432 + mm * 64 + kp) = pk2h(v0, v1);
    } else {                         // enc/dec 16x32 tiles, natural k (k>=16 zero)
        const int mm = tid >> 4;
        const int kp = (tid & 15) * 2;
        const bool rl = (kp < 16);
        const float eN0 = rl ? enc_n_w2[kp * 16 + mm] : 0.f;
        const float eN1 = rl ? enc_n_w2[(kp + 1) * 16 + mm] : 0.f;
        const float eE0 = rl ? enc_e_w2[kp * 16 + mm] : 0.f;
        const float eE1 = rl ? enc_e_w2[(kp + 1) * 16 + mm] : 0.f;
        const float d10 = rl ? dec_n_w1[kp * 16 + mm] : 0.f;
        const float d11 = rl ? dec_n_w1[(kp + 1) * 16 + mm] : 0.f;
        const float d20 = rl ? dec_n_w2[kp * 16 + mm] : 0.f;
        const float d21 = rl ? dec_n_w2[(kp + 1) * 16 + mm] : 0.f;
        *(unsigned*)(wg + 16384 + mm * 32 + kp) = pk2h(eN0, eN1);
        *(unsigned*)(wg + 16896 + mm * 32 + kp) = pk2h(eE0, eE1);
        *(unsigned*)(wg + 17408 + mm * 32 + kp) = pk2h(d10, d11);
        *(unsigned*)(wg + 17920 + mm * 32 + kp) = pk2h(d20, d21);
    }
}

// R29: R27 (best: main 66.0, VGPR=80, no spills, (256,3)) + W2 fragments
// PINNED in registers (8 f16x8 = 32 VGPRs -> ~112 of the ~170 budget).
// w2s is stage-invariant: pinning removes 4 of 8 ds_read_b128 per RK4
// stage (64/wave) and their lgkmcnt waits from the H->kc chain. w1 arrays
// (stage-varying scale) stay in LDS; sw shrinks 32->24 KB.
// Launch-bounds map (measured): (256,2)=18%occ/79.6; (256,3)=27%/66.0 BEST;
// (256,4)=34%occ but 73MB spills/76.0. (256,3) is the unique optimum.
// Tripwire: WRITE_SIZE must stay ~5.47 MB.
__global__ __launch_bounds__(256, 3)
void gnode_main(const float* __restrict__ nodes,
                const float* __restrict__ edges,
                const float* __restrict__ g,
                const float* __restrict__ enc_n_w1, const float* __restrict__ enc_n_b1,
                const float* __restrict__ enc_n_b2,
                const float* __restrict__ enc_e_w1, const float* __restrict__ enc_e_b1,
                const float* __restrict__ enc_e_b2,
                const float* __restrict__ node_out_b,
                const float* __restrict__ dec_n_b1, const float* __restrict__ dec_n_b2,
                const float* __restrict__ dec_n_w3, const float* __restrict__ dec_n_b3,
                const unsigned short* __restrict__ wg,
                float* __restrict__ out, float* __restrict__ npos)
{
    __shared__ __attribute__((aligned(16))) unsigned short dscr[WPB][640];
    __shared__ __attribute__((aligned(16))) unsigned short sw[12288];  // 24 KB: w1s|w1h2|w1h

    const int tid  = threadIdx.x;
    const int lane = tid & 63;
    const int wave = __builtin_amdgcn_readfirstlane(tid >> 6);
    const int m = lane & 15;
    const int q = lane >> 4;
    const bool q0 = (q == 0);
    unsigned short* const dscrw = &dscr[wave][0];

    // stage the 3 w1 arrays global->LDS (linear memcpy; pre-swizzled)
#pragma unroll
    for (int i = 0; i < 6; ++i)
        ((uint4*)sw)[tid + 256 * i] = ((const uint4*)wg)[tid + 256 * i];

    // pin W2 fragments in registers (slot index == lane -> coalesced 16B/lane)
    f16x8 w2f[2][4];
#pragma unroll
    for (int ct = 0; ct < 4; ++ct) {
        w2f[0][ct] = *(const f16x8*)(const void*)(wg + 12288 + ct * 1024 + lane * 8);
        w2f[1][ct] = *(const f16x8*)(const void*)(wg + 12288 + ct * 1024 + 512 + lane * 8);
    }

    const int nd = blockIdx.x * NPB + wave * 16 + m;
    const int nc = (nd < NN) ? nd : (NN - 1);

    // zero decoder-scratch k=16..31 (dw1/dw2 A-rows are zero there, but LDS
    // garbage could be NaN; 0 * NaN != 0)
    *(uint2*)(dscrw + m * 40 + 16 + q * 4) = make_uint2(0u, 0u);

    const f32x4 zero4 = {0.f, 0.f, 0.f, 0.f};
    const f16x2 h2z = {(_Float16)0.f, (_Float16)0.f};
    const f16x8 z8 = h8(h2z, h2z, h2z, h2z);

    // state: Y/ACC/KC f16x8 (2 each, B layout); U f32 (4 f32x4, D layout).
    f16x8 Y[2], ACC[2], KC[2];
    f32x4 U[4];

    // ---------------- encoder (3 f16 MFMAs) ----------------
    {
        const f16x8 wNf = *(const f16x8*)(const void*)(wg + 16384 + m * 32 + q * 8);
        const f16x8 wEf = *(const f16x8*)(const void*)(wg + 16896 + m * 32 + q * 8);
        f32x4 bN, bE;
#pragma unroll
        for (int r = 0; r < 4; ++r) { bN[r] = enc_n_b2[q * 4 + r]; bE[r] = enc_e_b2[q * 4 + r]; }
        const float g0v = g[0], g1v = g[1];

        const int node = nc;
        f32x4 e0, e1, e2;
        {
            float nf[5];
#pragma unroll
            for (int c = 0; c < 5; ++c) nf[c] = nodes[node * 5 + c];
            f16x8 bfr = z8;
            if (q < 2) {
                float hv[8];
#pragma unroll
                for (int j = 0; j < 8; ++j) {
                    const int d = q * 8 + j;
                    float s = enc_n_b1[d];
#pragma unroll
                    for (int c = 0; c < 5; ++c) s = fmaf(nf[c], enc_n_w1[c * 16 + d], s);
                    hv[j] = swishf(s);
                }
                bfr = h8(c2h(hv[0], hv[1]), c2h(hv[2], hv[3]),
                         c2h(hv[4], hv[5]), c2h(hv[6], hv[7]));
            }
            e0 = __builtin_amdgcn_mfma_f32_16x16x32_f16(wNf, bfr, bN, 0, 0, 0);
        }
        {
            const float ev = (node < EE) ? edges[node] : 0.0f;
            f16x8 bfr = z8;
            if (q < 2) {
                float hv[8];
#pragma unroll
                for (int j = 0; j < 8; ++j) {
                    const int d = q * 8 + j;
                    hv[j] = swishf(fmaf(ev, enc_e_w1[d], enc_e_b1[d]));
                }
                bfr = h8(c2h(hv[0], hv[1]), c2h(hv[2], hv[3]),
                         c2h(hv[4], hv[5]), c2h(hv[6], hv[7]));
            }
            e1 = __builtin_amdgcn_mfma_f32_16x16x32_f16(wEf, bfr, bE, 0, 0, 0);
            if (node == NN - 1) e1 = zero4;
        }
        {
            const float ev = (node > 0) ? edges[node - 1] : 0.0f;
            f16x8 bfr = z8;
            if (q < 2) {
                float hv[8];
#pragma unroll
                for (int j = 0; j < 8; ++j) {
                    const int d = q * 8 + j;
                    hv[j] = swishf(fmaf(ev, enc_e_w1[d], enc_e_b1[d]));
                }
                bfr = h8(c2h(hv[0], hv[1]), c2h(hv[2], hv[3]),
                         c2h(hv[4], hv[5]), c2h(hv[6], hv[7]));
            }
            e2 = __builtin_amdgcn_mfma_f32_16x16x32_f16(wEf, bfr, bE, 0, 0, 0);
            if (node == 0) e2 = zero4;
        }
        Y[0] = h8(c2h(e0[0], e0[1]), c2h(e0[2], e0[3]),
                  c2h(e1[0], e1[1]), c2h(e1[2], e1[3]));
        Y[1] = h8(c2h(e2[0], e2[1]), c2h(e2[2], e2[3]),
                  q0 ? c2h(g0v, g1v) : h2z, h2z);
    }

    __syncthreads();    // sw ready before RK4

    // per-lane LDS fragment base: lane (m,q) -> slot q*16+m == lane
    // (lane-linear: wave's b128 read covers 1024 contiguous bytes)
    const unsigned short* const swl = sw + lane * 8;

    // ---------------- RK4 (4 steps x 4 fully-unrolled stages) ----------
    const float hh = 1.0f / NSTEPS;
    float t0 = 0.0f;
    const unsigned inj1 = 0x00003C00u;   // f16 (1.0, 0.0): Δt/cb ≡ 1, bias from U

#pragma clang loop unroll(disable)
    for (int step = 0; step < NSTEPS; ++step) {
#pragma unroll
        for (int s = 0; s < 4; ++s) {
            f32x4 hc[4];
            if (s == 0) {
                // U = W1ext · [Y, t0, 1]  (once per RK4 step; hc(0) = U)
                const f16x8 y1x = setw(Y[1], q0, pk2h(t0, 1.0f));
#pragma unroll
                for (int ct = 0; ct < 4; ++ct) {
                    const f16x8 wa = *(const f16x8*)(const void*)(swl + ct * 1024);
                    const f16x8 wb = *(const f16x8*)(const void*)(swl + ct * 1024 + 512);
                    f32x4 c0 = __builtin_amdgcn_mfma_f32_16x16x32_f16(wa, Y[0], zero4, 0, 0, 0);
                    U[ct] = __builtin_amdgcn_mfma_f32_16x16x32_f16(wb, y1x, c0, 0, 0, 0);
                    hc[ct] = U[ct];
                }
            } else {
                // hc(s) = U + (cb_{s-1}·W1)·KC(s-1); cb=h/2 for s=1,2; cb=h for s=3
                const int cboff = (s == 3) ? 8192 : 4096;
#pragma unroll
                for (int ct = 0; ct < 4; ++ct) {
                    const f16x8 wa = *(const f16x8*)(const void*)(swl + cboff + ct * 1024);
                    const f16x8 wb = *(const f16x8*)(const void*)(swl + cboff + ct * 1024 + 512);
                    f32x4 c0 = __builtin_amdgcn_mfma_f32_16x16x32_f16(wa, KC[0], U[ct], 0, 0, 0);
                    hc[ct] = __builtin_amdgcn_mfma_f32_16x16x32_f16(wb, KC[1], c0, 0, 0, 0);
                }
            }

            f16x8 H[2];
            H[0] = h8(relu2(c2h(hc[0][0], hc[0][1])),
                      relu2(c2h(hc[0][2], hc[0][3])),
                      relu2(c2h(hc[1][0], hc[1][1])),
                      relu2(c2h(hc[1][2], hc[1][3])));
            f16x8 h1 = h8(relu2(c2h(hc[2][0], hc[2][1])),
                          relu2(c2h(hc[2][2], hc[2][3])),
                          relu2(c2h(hc[3][0], hc[3][1])),
                          relu2(c2h(hc[3][2], hc[3][3])));
            H[1] = setw(h1, q0, 0x3C003C00u);   // hidden bias slot (dim 50) = 1

            f32x4 kc[4];
#pragma unroll
            for (int ct = 0; ct < 4; ++ct) {
                f32x4 c0 = __builtin_amdgcn_mfma_f32_16x16x32_f16(w2f[0][ct], H[0], zero4, 0, 0, 0);
                kc[ct] = __builtin_amdgcn_mfma_f32_16x16x32_f16(w2f[1][ct], H[1], c0, 0, 0, 0);
            }

            const float ca = (s == 0 || s == 3) ? hh / 6.0f : hh / 3.0f;
            const f16x2 cah = c2h(ca, ca);
            const f16x8 ca8 = h8(cah, cah, cah, cah);

            KC[0] = h8(c2h(kc[0][0], kc[0][1]), c2h(kc[0][2], kc[0][3]),
                       c2h(kc[1][0], kc[1][1]), c2h(kc[1][2], kc[1][3]));
            KC[1] = h8(c2h(kc[2][0], kc[2][1]), c2h(kc[2][2], kc[2][3]),
                       c2h(kc[3][0], kc[3][1]), c2h(kc[3][2], kc[3][3]));
            if (s == 0) {
                ACC[0] = ca8 * KC[0] + Y[0];
                ACC[1] = ca8 * KC[1] + Y[1];
            } else {
                ACC[0] = ca8 * KC[0] + ACC[0];
                ACC[1] = ca8 * KC[1] + ACC[1];
            }
            if (s < 3) {
                KC[1] = setw(KC[1], q0, inj1);   // Δt/cb = 1 into slot 38
            } else {
                Y[0] = ACC[0];
                Y[1] = ACC[1];
            }
        }
        t0 += hh;
    }

    // ------------- decoder (4 f16 MFMAs; weights loaded HERE) -------
    const f16x8 dw1 = *(const f16x8*)(const void*)(wg + 17408 + m * 32 + q * 8);
    const f16x8 dw2 = *(const f16x8*)(const void*)(wg + 17920 + m * 32 + q * 8);
    const f16x8 ow0 = *(const f16x8*)(const void*)(wg + 18432 + m * 64 + q * 8);
    const f16x8 ow1 = *(const f16x8*)(const void*)(wg + 18432 + m * 64 + 32 + q * 8);
    f32x4 bO, bD1, bD2;
    float w3v[4];
#pragma unroll
    for (int r = 0; r < 4; ++r) {
        bO[r]  = node_out_b[q * 4 + r];
        bD1[r] = dec_n_b1[q * 4 + r];
        bD2[r] = dec_n_b2[q * 4 + r];
        w3v[r] = dec_n_w3[q * 4 + r];
    }

    {
        f32x4 nl2 = __builtin_amdgcn_mfma_f32_16x16x32_f16(ow0, Y[0], bO, 0, 0, 0);
        nl2       = __builtin_amdgcn_mfma_f32_16x16x32_f16(ow1, Y[1], nl2, 0, 0, 0);

        *(uint2*)(dscrw + m * 40 + q * 4) =
            make_uint2(pk2h(nl2[0], nl2[1]), pk2h(nl2[2], nl2[3]));
        f16x8 nB = *(const f16x8*)(const void*)(dscrw + m * 40 + q * 8);
        f32x4 dh = __builtin_amdgcn_mfma_f32_16x16x32_f16(dw1, nB, bD1, 0, 0, 0);
#pragma unroll
        for (int r = 0; r < 4; ++r) dh[r] = swishf(dh[r]);

        *(uint2*)(dscrw + m * 40 + q * 4) =
            make_uint2(pk2h(dh[0], dh[1]), pk2h(dh[2], dh[3]));
        f16x8 dB = *(const f16x8*)(const void*)(dscrw + m * 40 + q * 8);
        f32x4 dh2 = __builtin_amdgcn_mfma_f32_16x16x32_f16(dw2, dB, bD2, 0, 0, 0);
#pragma unroll
        for (int r = 0; r < 4; ++r) dh2[r] = swishf(dh2[r]);

        float p = dh2[0] * w3v[0];
        p = fmaf(dh2[1], w3v[1], p);
        p = fmaf(dh2[2], w3v[2], p);
        p = fmaf(dh2[3], w3v[3], p);
        p += __shfl_xor(p, 16);
        p += __shfl_xor(p, 32);
        p += dec_n_b3[0];

        const int node = nd;
        if (q0 && node < NN) {
            const float cur_pos = nodes[node * 5 + 0];
            const float c2 = nodes[node * 5 + 2];
            const float c3 = nodes[node * 5 + 3];
            const float cur_vel = nodes[node * 5 + 4];
            const float next_vel = fmaf(p, DTC, cur_vel);
            const float next_pos = fmaf(next_vel, DTC, cur_pos);
            out[node * 6 + 0] = next_pos;
            out[node * 6 + 1] = c2;
            out[node * 6 + 2] = c3;
            out[node * 6 + 3] = cur_vel;
            out[node * 6 + 4] = next_vel;
            out[node * 6 + 5] = p;
            npos[node] = next_pos;
        }
    }
}

// third pass: next_edges = diff(next_pos) from packed npos (coalesced), g_new
__global__ void gnode_edges(const float* __restrict__ npos,
                            float* __restrict__ out,
                            const float* __restrict__ g)
{
    const int e = blockIdx.x * blockDim.x + threadIdx.x;
    if (e < EE) {
        out[NN * 6 + e] = npos[e + 1] - npos[e];
    }
    if (e == 0) {
        out[NN * 6 + EE]     = g[0] + 1.0f;
        out[NN * 6 + EE + 1] = g[1];
    }
}

extern "C" void kernel_launch(void* const* d_in, const int* in_sizes, int n_in,
                              void* d_out, int out_size, void* d_ws, size_t ws_size,
                              hipStream_t stream) {
    const float* nodes      = (const float*)d_in[0];
    const float* edges      = (const float*)d_in[1];
    const float* g          = (const float*)d_in[2];
    const float* enc_n_w1   = (const float*)d_in[3];
    const float* enc_n_b1   = (const float*)d_in[4];
    const float* enc_n_w2   = (const float*)d_in[5];
    const float* enc_n_b2   = (const float*)d_in[6];
    const float* enc_e_w1   = (const float*)d_in[7];
    const float* enc_e_b1   = (const float*)d_in[8];
    const float* enc_e_w2   = (const float*)d_in[9];
    const float* enc_e_b2   = (const float*)d_in[10];
    const float* ode_w1     = (const float*)d_in[11];
    const float* ode_b1     = (const float*)d_in[12];
    const float* ode_w2     = (const float*)d_in[13];
    const float* ode_b2     = (const float*)d_in[14];
    const float* node_out_w = (const float*)d_in[15];
    const float* node_out_b = (const float*)d_in[16];
    const float* dec_n_w1   = (const float*)d_in[17];
    const float* dec_n_b1   = (const float*)d_in[18];
    const float* dec_n_w2   = (const float*)d_in[19];
    const float* dec_n_b2   = (const float*)d_in[20];
    const float* dec_n_w3   = (const float*)d_in[21];
    const float* dec_n_b3   = (const float*)d_in[22];
    float* out  = (float*)d_out;
    float* npos = (float*)d_ws;                               // NN floats
    unsigned short* wg = (unsigned short*)((char*)d_ws + (size_t)NN * 4);  // 38 KB

    gnode_weights<<<11, 256, 0, stream>>>(
        ode_w1, ode_b1, ode_w2, ode_b2,
        enc_n_w2, enc_e_w2, dec_n_w1, dec_n_w2, node_out_w, wg);

    gnode_main<<<GRID, 256, 0, stream>>>(
        nodes, edges, g,
        enc_n_w1, enc_n_b1, enc_n_b2,
        enc_e_w1, enc_e_b1, enc_e_b2,
        node_out_b, dec_n_b1, dec_n_b2, dec_n_w3, dec_n_b3,
        wg, out, npos);

    gnode_edges<<<(EE + 255) / 256, 256, 0, stream>>>(npos, out, g);
}

// Round 14
// 156.794 us; speedup vs baseline: 1.1116x; 1.0246x over previous
//
#include <hip/hip_runtime.h>

#define NN 200000
#define EE (NN - 1)
#define NSTEPS 4
#define DTC 0.01f
#define WPB 4
#define NPB 64            // nodes per block (1 tile of 16 per wave x 4 waves)
#define GRID 3125         // 200000/64 exact

typedef __attribute__((ext_vector_type(8))) _Float16 f16x8;
typedef __attribute__((ext_vector_type(2))) _Float16 f16x2;
typedef __attribute__((ext_vector_type(4))) float f32x4;

struct H4 { f16x2 a, b, c, d; };

__device__ __forceinline__ f16x2 c2h(float lo, float hi) {
    return __builtin_bit_cast(f16x2, __builtin_amdgcn_cvt_pkrtz(lo, hi)); // 1 instr
}
__device__ __forceinline__ unsigned pk2h(float lo, float hi) {
    return __builtin_bit_cast(unsigned, __builtin_amdgcn_cvt_pkrtz(lo, hi));
}
__device__ __forceinline__ f16x8 h8(f16x2 a, f16x2 b, f16x2 c, f16x2 d) {
    H4 t{a, b, c, d};
    return __builtin_bit_cast(f16x8, t);
}
__device__ __forceinline__ f16x2 relu2(f16x2 v) {   // v_pk_max_f16 vs 0
    f16x2 r;
    asm("v_pk_max_f16 %0, %1, 0" : "=v"(r) : "v"(v));
    return r;
}
__device__ __forceinline__ float swishf(float x) { return x / (1.0f + __expf(-x)); }

// dimension relabeling (verified R8+): C output (ct,q,r) packs directly into
// the next GEMM's B operand slots; B pos k <-> original dim permk(k).
__device__ __forceinline__ int permk(int k) {
    return (k & 0x23) | ((k & 4) << 2) | ((k & 0x18) >> 1);
}

// set dword 3 (f16 pair 3) of an f16x8 where cond holds: 1 v_cndmask
__device__ __forceinline__ f16x8 setw(f16x8 v, bool cond, unsigned nw) {
    uint4 u = __builtin_bit_cast(uint4, v);
    u.w = cond ? nw : u.w;
    return __builtin_bit_cast(f16x8, u);
}

// ws layout (ushort offsets within the weight region):
// [0,4096)      w1s   (W1ext^T, unscaled — LDS; used once/step for U)
// [4096,8192)   w1h2  (W1ext^T * h/2 — PINNED in registers; s=1,2 direct,
//                      s=3 via doubled KC: h*W1*KC == (h/2*W1)*(2*KC), exact)
// [8192,12288)  w2s   (PINNED in registers)
// [12288,12800) encN ; [12800,13312) encE ; [13312,13824) dW1 ;
// [13824,14336) dW2 ; [14336,15360) outW
//
// All w1*/w2 arrays use the lane-linear swizzle (R22/R23-verified conflict-
// free): frag elem (od=ct*16+mm, k=kt*32+qq*8+jj) at ushort idx
// ct*1024 + kt*512 + (qq*16+mm)*8 + jj  (slot index == lane id).
__global__ void gnode_weights(const float* __restrict__ ode_w1, const float* __restrict__ ode_b1,
                              const float* __restrict__ ode_w2, const float* __restrict__ ode_b2,
                              const float* __restrict__ enc_n_w2, const float* __restrict__ enc_e_w2,
                              const float* __restrict__ dec_n_w1, const float* __restrict__ dec_n_w2,
                              const float* __restrict__ node_out_w,
                              unsigned short* __restrict__ wg)
{
    const int b = blockIdx.x;
    const int tid = threadIdx.x;
    const float hh = 1.0f / NSTEPS;
    if (b < 8) {                     // W1ext^T / W2ext^T, permuted columns
        const int i = tid + b * 256;
        const int od = i >> 5;
        const int k2 = (i & 31) * 2;
        const int s0 = permk(k2);
        const int s1 = s0 + 1;
        float a0 = 0.f, a1 = 0.f, b0 = 0.f, b1 = 0.f;
        if (od < 50) {
            a0 = (s0 <= 50) ? ode_w1[s0 * 50 + od] : 0.f;
            a1 = (s1 <= 50) ? ode_w1[s1 * 50 + od]
                            : ((s1 == 51) ? ode_b1[od] : 0.f);
            b0 = (s0 < 50) ? ode_w2[s0 * 50 + od]
                           : ((s0 == 50) ? ode_b2[od] : 0.f);
            b1 = (s1 < 50) ? ode_w2[s1 * 50 + od] : 0.f;
        }
        // lane-linear swizzled destination (see comment above)
        const int ct = od >> 4;
        const int mm = od & 15;
        const int kt = k2 >> 5;
        const int qq = (k2 >> 3) & 3;
        const int jj = k2 & 7;
        const int didx = ct * 1024 + kt * 512 + (qq * 16 + mm) * 8 + jj;
        *(unsigned*)(wg + didx)         = pk2h(a0, a1);
        *(unsigned*)(wg + 4096 + didx)  = pk2h(a0 * (0.5f * hh), a1 * (0.5f * hh));
        *(unsigned*)(wg + 8192 + didx)  = pk2h(b0, b1);
    } else if (b < 10) {             // node_out_w^T 16x64, permuted cols
        const int i = tid + (b - 8) * 256;
        const int mm = i >> 5;
        const int kp = (i & 31) * 2;
        const int s0 = permk(kp);
        const float v0 = (s0     < 50) ? node_out_w[s0 * 16 + mm] : 0.f;
        const float v1 = (s0 + 1 < 50) ? node_out_w[(s0 + 1) * 16 + mm] : 0.f;
        *(unsigned*)(wg + 14336 + mm * 64 + kp) = pk2h(v0, v1);
    } else {                         // enc/dec 16x32 tiles, natural k (k>=16 zero)
        const int mm = tid >> 4;
        const int kp = (tid & 15) * 2;
        const bool rl = (kp < 16);
        const float eN0 = rl ? enc_n_w2[kp * 16 + mm] : 0.f;
        const float eN1 = rl ? enc_n_w2[(kp + 1) * 16 + mm] : 0.f;
        const float eE0 = rl ? enc_e_w2[kp * 16 + mm] : 0.f;
        const float eE1 = rl ? enc_e_w2[(kp + 1) * 16 + mm] : 0.f;
        const float d10 = rl ? dec_n_w1[kp * 16 + mm] : 0.f;
        const float d11 = rl ? dec_n_w1[(kp + 1) * 16 + mm] : 0.f;
        const float d20 = rl ? dec_n_w2[kp * 16 + mm] : 0.f;
        const float d21 = rl ? dec_n_w2[(kp + 1) * 16 + mm] : 0.f;
        *(unsigned*)(wg + 12288 + mm * 32 + kp) = pk2h(eN0, eN1);
        *(unsigned*)(wg + 12800 + mm * 32 + kp) = pk2h(eE0, eE1);
        *(unsigned*)(wg + 13312 + mm * 32 + kp) = pk2h(d10, d11);
        *(unsigned*)(wg + 13824 + mm * 32 + kp) = pk2h(d20, d21);
    }
}

// R30: R29 (best: main 58.5, VGPR=80) + W1h2 ALSO pinned (8 f16x8 = 32 more
// VGPRs -> ~112 of the ~170 budget). s=1,2 use pinned w1h2 directly; s=3
// uses pinned w1h2 with DOUBLED KC (h*W1*X == (h/2*W1)*(2X); f16 doubling
// is exact incl. the injected 1.0->2.0 t-slot since (h/2)*2 = h). RK4 LDS
// reads drop 32->8 per step (only s=0's w1s remains); stages 1-3 are pure
// register dataflow, no lgkmcnt in the chain.
// Launch-bounds map (measured): (256,2)=18%occ; (256,3)=27% BEST; (256,4)=
// spills. Tripwire: WRITE_SIZE must stay ~5.47 MB, else revert to R29.
__global__ __launch_bounds__(256, 3)
void gnode_main(const float* __restrict__ nodes,
                const float* __restrict__ edges,
                const float* __restrict__ g,
                const float* __restrict__ enc_n_w1, const float* __restrict__ enc_n_b1,
                const float* __restrict__ enc_n_b2,
                const float* __restrict__ enc_e_w1, const float* __restrict__ enc_e_b1,
                const float* __restrict__ enc_e_b2,
                const float* __restrict__ node_out_b,
                const float* __restrict__ dec_n_b1, const float* __restrict__ dec_n_b2,
                const float* __restrict__ dec_n_w3, const float* __restrict__ dec_n_b3,
                const unsigned short* __restrict__ wg,
                float* __restrict__ out, float* __restrict__ npos)
{
    __shared__ __attribute__((aligned(16))) unsigned short dscr[WPB][640];
    __shared__ __attribute__((aligned(16))) unsigned short sw[4096];  // 8 KB: w1s only

    const int tid  = threadIdx.x;
    const int lane = tid & 63;
    const int wave = __builtin_amdgcn_readfirstlane(tid >> 6);
    const int m = lane & 15;
    const int q = lane >> 4;
    const bool q0 = (q == 0);
    unsigned short* const dscrw = &dscr[wave][0];

    // stage w1s global->LDS (linear memcpy; pre-swizzled)
#pragma unroll
    for (int i = 0; i < 2; ++i)
        ((uint4*)sw)[tid + 256 * i] = ((const uint4*)wg)[tid + 256 * i];

    // pin W1h2 + W2 fragments in registers (slot index == lane -> coalesced)
    f16x8 w1f2[2][4], w2f[2][4];
#pragma unroll
    for (int ct = 0; ct < 4; ++ct) {
        w1f2[0][ct] = *(const f16x8*)(const void*)(wg + 4096 + ct * 1024 + lane * 8);
        w1f2[1][ct] = *(const f16x8*)(const void*)(wg + 4096 + ct * 1024 + 512 + lane * 8);
        w2f[0][ct]  = *(const f16x8*)(const void*)(wg + 8192 + ct * 1024 + lane * 8);
        w2f[1][ct]  = *(const f16x8*)(const void*)(wg + 8192 + ct * 1024 + 512 + lane * 8);
    }

    const int nd = blockIdx.x * NPB + wave * 16 + m;
    const int nc = (nd < NN) ? nd : (NN - 1);

    // zero decoder-scratch k=16..31 (dw1/dw2 A-rows are zero there, but LDS
    // garbage could be NaN; 0 * NaN != 0)
    *(uint2*)(dscrw + m * 40 + 16 + q * 4) = make_uint2(0u, 0u);

    const f32x4 zero4 = {0.f, 0.f, 0.f, 0.f};
    const f16x2 h2z = {(_Float16)0.f, (_Float16)0.f};
    const f16x8 z8 = h8(h2z, h2z, h2z, h2z);

    // state: Y/ACC/KC f16x8 (2 each, B layout); U f32 (4 f32x4, D layout).
    f16x8 Y[2], ACC[2], KC[2];
    f32x4 U[4];

    // ---------------- encoder (3 f16 MFMAs) ----------------
    {
        const f16x8 wNf = *(const f16x8*)(const void*)(wg + 12288 + m * 32 + q * 8);
        const f16x8 wEf = *(const f16x8*)(const void*)(wg + 12800 + m * 32 + q * 8);
        f32x4 bN, bE;
#pragma unroll
        for (int r = 0; r < 4; ++r) { bN[r] = enc_n_b2[q * 4 + r]; bE[r] = enc_e_b2[q * 4 + r]; }
        const float g0v = g[0], g1v = g[1];

        const int node = nc;
        f32x4 e0, e1, e2;
        {
            float nf[5];
#pragma unroll
            for (int c = 0; c < 5; ++c) nf[c] = nodes[node * 5 + c];
            f16x8 bfr = z8;
            if (q < 2) {
                float hv[8];
#pragma unroll
                for (int j = 0; j < 8; ++j) {
                    const int d = q * 8 + j;
                    float s = enc_n_b1[d];
#pragma unroll
                    for (int c = 0; c < 5; ++c) s = fmaf(nf[c], enc_n_w1[c * 16 + d], s);
                    hv[j] = swishf(s);
                }
                bfr = h8(c2h(hv[0], hv[1]), c2h(hv[2], hv[3]),
                         c2h(hv[4], hv[5]), c2h(hv[6], hv[7]));
            }
            e0 = __builtin_amdgcn_mfma_f32_16x16x32_f16(wNf, bfr, bN, 0, 0, 0);
        }
        {
            const float ev = (node < EE) ? edges[node] : 0.0f;
            f16x8 bfr = z8;
            if (q < 2) {
                float hv[8];
#pragma unroll
                for (int j = 0; j < 8; ++j) {
                    const int d = q * 8 + j;
                    hv[j] = swishf(fmaf(ev, enc_e_w1[d], enc_e_b1[d]));
                }
                bfr = h8(c2h(hv[0], hv[1]), c2h(hv[2], hv[3]),
                         c2h(hv[4], hv[5]), c2h(hv[6], hv[7]));
            }
            e1 = __builtin_amdgcn_mfma_f32_16x16x32_f16(wEf, bfr, bE, 0, 0, 0);
            if (node == NN - 1) e1 = zero4;
        }
        {
            const float ev = (node > 0) ? edges[node - 1] : 0.0f;
            f16x8 bfr = z8;
            if (q < 2) {
                float hv[8];
#pragma unroll
                for (int j = 0; j < 8; ++j) {
                    const int d = q * 8 + j;
                    hv[j] = swishf(fmaf(ev, enc_e_w1[d], enc_e_b1[d]));
                }
                bfr = h8(c2h(hv[0], hv[1]), c2h(hv[2], hv[3]),
                         c2h(hv[4], hv[5]), c2h(hv[6], hv[7]));
            }
            e2 = __builtin_amdgcn_mfma_f32_16x16x32_f16(wEf, bfr, bE, 0, 0, 0);
            if (node == 0) e2 = zero4;
        }
        Y[0] = h8(c2h(e0[0], e0[1]), c2h(e0[2], e0[3]),
                  c2h(e1[0], e1[1]), c2h(e1[2], e1[3]));
        Y[1] = h8(c2h(e2[0], e2[1]), c2h(e2[2], e2[3]),
                  q0 ? c2h(g0v, g1v) : h2z, h2z);
    }

    __syncthreads();    // sw ready before RK4

    // per-lane LDS fragment base: slot index == lane (conflict-free b128)
    const unsigned short* const swl = sw + lane * 8;

    // ---------------- RK4 (4 steps x 4 fully-unrolled stages) ----------
    const float hh = 1.0f / NSTEPS;
    float t0 = 0.0f;
    const unsigned inj1 = 0x00003C00u;   // f16 (1.0, 0.0): Δt/cb ≡ 1, bias from U

#pragma clang loop unroll(disable)
    for (int step = 0; step < NSTEPS; ++step) {
#pragma unroll
        for (int s = 0; s < 4; ++s) {
            f32x4 hc[4];
            if (s == 0) {
                // U = W1ext · [Y, t0, 1]  (once per RK4 step; hc(0) = U)
                const f16x8 y1x = setw(Y[1], q0, pk2h(t0, 1.0f));
#pragma unroll
                for (int ct = 0; ct < 4; ++ct) {
                    const f16x8 wa = *(const f16x8*)(const void*)(swl + ct * 1024);
                    const f16x8 wb = *(const f16x8*)(const void*)(swl + ct * 1024 + 512);
                    f32x4 c0 = __builtin_amdgcn_mfma_f32_16x16x32_f16(wa, Y[0], zero4, 0, 0, 0);
                    U[ct] = __builtin_amdgcn_mfma_f32_16x16x32_f16(wb, y1x, c0, 0, 0, 0);
                    hc[ct] = U[ct];
                }
            } else if (s < 3) {
                // hc(s) = U + (h/2·W1)·KC(s-1)  — pinned w1h2
#pragma unroll
                for (int ct = 0; ct < 4; ++ct) {
                    f32x4 c0 = __builtin_amdgcn_mfma_f32_16x16x32_f16(w1f2[0][ct], KC[0], U[ct], 0, 0, 0);
                    hc[ct] = __builtin_amdgcn_mfma_f32_16x16x32_f16(w1f2[1][ct], KC[1], c0, 0, 0, 0);
                }
            } else {
                // hc(3) = U + (h·W1)·KC(2) == U + (h/2·W1)·(2·KC) — f16-exact
                const f16x8 kd0 = KC[0] + KC[0];
                const f16x8 kd1 = KC[1] + KC[1];
#pragma unroll
                for (int ct = 0; ct < 4; ++ct) {
                    f32x4 c0 = __builtin_amdgcn_mfma_f32_16x16x32_f16(w1f2[0][ct], kd0, U[ct], 0, 0, 0);
                    hc[ct] = __builtin_amdgcn_mfma_f32_16x16x32_f16(w1f2[1][ct], kd1, c0, 0, 0, 0);
                }
            }

            f16x8 H[2];
            H[0] = h8(relu2(c2h(hc[0][0], hc[0][1])),
                      relu2(c2h(hc[0][2], hc[0][3])),
                      relu2(c2h(hc[1][0], hc[1][1])),
                      relu2(c2h(hc[1][2], hc[1][3])));
            f16x8 h1 = h8(relu2(c2h(hc[2][0], hc[2][1])),
                          relu2(c2h(hc[2][2], hc[2][3])),
                          relu2(c2h(hc[3][0], hc[3][1])),
                          relu2(c2h(hc[3][2], hc[3][3])));
            H[1] = setw(h1, q0, 0x3C003C00u);   // hidden bias slot (dim 50) = 1

            f32x4 kc[4];
#pragma unroll
            for (int ct = 0; ct < 4; ++ct) {
                f32x4 c0 = __builtin_amdgcn_mfma_f32_16x16x32_f16(w2f[0][ct], H[0], zero4, 0, 0, 0);
                kc[ct] = __builtin_amdgcn_mfma_f32_16x16x32_f16(w2f[1][ct], H[1], c0, 0, 0, 0);
            }

            const float ca = (s == 0 || s == 3) ? hh / 6.0f : hh / 3.0f;
            const f16x2 cah = c2h(ca, ca);
            const f16x8 ca8 = h8(cah, cah, cah, cah);

            KC[0] = h8(c2h(kc[0][0], kc[0][1]), c2h(kc[0][2], kc[0][3]),
                       c2h(kc[1][0], kc[1][1]), c2h(kc[1][2], kc[1][3]));
            KC[1] = h8(c2h(kc[2][0], kc[2][1]), c2h(kc[2][2], kc[2][3]),
                       c2h(kc[3][0], kc[3][1]), c2h(kc[3][2], kc[3][3]));
            if (s == 0) {
                ACC[0] = ca8 * KC[0] + Y[0];
                ACC[1] = ca8 * KC[1] + Y[1];
            } else {
                ACC[0] = ca8 * KC[0] + ACC[0];
                ACC[1] = ca8 * KC[1] + ACC[1];
            }
            if (s < 3) {
                KC[1] = setw(KC[1], q0, inj1);   // Δt/cb = 1 into slot 38
            } else {
                Y[0] = ACC[0];
                Y[1] = ACC[1];
            }
        }
        t0 += hh;
    }

    // ------------- decoder (4 f16 MFMAs; weights loaded HERE) -------
    const f16x8 dw1 = *(const f16x8*)(const void*)(wg + 13312 + m * 32 + q * 8);
    const f16x8 dw2 = *(const f16x8*)(const void*)(wg + 13824 + m * 32 + q * 8);
    const f16x8 ow0 = *(const f16x8*)(const void*)(wg + 14336 + m * 64 + q * 8);
    const f16x8 ow1 = *(const f16x8*)(const void*)(wg + 14336 + m * 64 + 32 + q * 8);
    f32x4 bO, bD1, bD2;
    float w3v[4];
#pragma unroll
    for (int r = 0; r < 4; ++r) {
        bO[r]  = node_out_b[q * 4 + r];
        bD1[r] = dec_n_b1[q * 4 + r];
        bD2[r] = dec_n_b2[q * 4 + r];
        w3v[r] = dec_n_w3[q * 4 + r];
    }

    {
        f32x4 nl2 = __builtin_amdgcn_mfma_f32_16x16x32_f16(ow0, Y[0], bO, 0, 0, 0);
        nl2       = __builtin_amdgcn_mfma_f32_16x16x32_f16(ow1, Y[1], nl2, 0, 0, 0);

        *(uint2*)(dscrw + m * 40 + q * 4) =
            make_uint2(pk2h(nl2[0], nl2[1]), pk2h(nl2[2], nl2[3]));
        f16x8 nB = *(const f16x8*)(const void*)(dscrw + m * 40 + q * 8);
        f32x4 dh = __builtin_amdgcn_mfma_f32_16x16x32_f16(dw1, nB, bD1, 0, 0, 0);
#pragma unroll
        for (int r = 0; r < 4; ++r) dh[r] = swishf(dh[r]);

        *(uint2*)(dscrw + m * 40 + q * 4) =
            make_uint2(pk2h(dh[0], dh[1]), pk2h(dh[2], dh[3]));
        f16x8 dB = *(const f16x8*)(const void*)(dscrw + m * 40 + q * 8);
        f32x4 dh2 = __builtin_amdgcn_mfma_f32_16x16x32_f16(dw2, dB, bD2, 0, 0, 0);
#pragma unroll
        for (int r = 0; r < 4; ++r) dh2[r] = swishf(dh2[r]);

        float p = dh2[0] * w3v[0];
        p = fmaf(dh2[1], w3v[1], p);
        p = fmaf(dh2[2], w3v[2], p);
        p = fmaf(dh2[3], w3v[3], p);
        p += __shfl_xor(p, 16);
        p += __shfl_xor(p, 32);
        p += dec_n_b3[0];

        const int node = nd;
        if (q0 && node < NN) {
            const float cur_pos = nodes[node * 5 + 0];
            const float c2 = nodes[node * 5 + 2];
            const float c3 = nodes[node * 5 + 3];
            const float cur_vel = nodes[node * 5 + 4];
            const float next_vel = fmaf(p, DTC, cur_vel);
            const float next_pos = fmaf(next_vel, DTC, cur_pos);
            out[node * 6 + 0] = next_pos;
            out[node * 6 + 1] = c2;
            out[node * 6 + 2] = c3;
            out[node * 6 + 3] = cur_vel;
            out[node * 6 + 4] = next_vel;
            out[node * 6 + 5] = p;
            npos[node] = next_pos;
        }
    }
}

// third pass: next_edges = diff(next_pos) from packed npos (coalesced), g_new
__global__ void gnode_edges(const float* __restrict__ npos,
                            float* __restrict__ out,
                            const float* __restrict__ g)
{
    const int e = blockIdx.x * blockDim.x + threadIdx.x;
    if (e < EE) {
        out[NN * 6 + e] = npos[e + 1] - npos[e];
    }
    if (e == 0) {
        out[NN * 6 + EE]     = g[0] + 1.0f;
        out[NN * 6 + EE + 1] = g[1];
    }
}

extern "C" void kernel_launch(void* const* d_in, const int* in_sizes, int n_in,
                              void* d_out, int out_size, void* d_ws, size_t ws_size,
                              hipStream_t stream) {
    const float* nodes      = (const float*)d_in[0];
    const float* edges      = (const float*)d_in[1];
    const float* g          = (const float*)d_in[2];
    const float* enc_n_w1   = (const float*)d_in[3];
    const float* enc_n_b1   = (const float*)d_in[4];
    const float* enc_n_w2   = (const float*)d_in[5];
    const float* enc_n_b2   = (const float*)d_in[6];
    const float* enc_e_w1   = (const float*)d_in[7];
    const float* enc_e_b1   = (const float*)d_in[8];
    const float* enc_e_w2   = (const float*)d_in[9];
    const float* enc_e_b2   = (const float*)d_in[10];
    const float* ode_w1     = (const float*)d_in[11];
    const float* ode_b1     = (const float*)d_in[12];
    const float* ode_w2     = (const float*)d_in[13];
    const float* ode_b2     = (const float*)d_in[14];
    const float* node_out_w = (const float*)d_in[15];
    const float* node_out_b = (const float*)d_in[16];
    const float* dec_n_w1   = (const float*)d_in[17];
    const float* dec_n_b1   = (const float*)d_in[18];
    const float* dec_n_w2   = (const float*)d_in[19];
    const float* dec_n_b2   = (const float*)d_in[20];
    const float* dec_n_w3   = (const float*)d_in[21];
    const float* dec_n_b3   = (const float*)d_in[22];
    float* out  = (float*)d_out;
    float* npos = (float*)d_ws;                               // NN floats
    unsigned short* wg = (unsigned short*)((char*)d_ws + (size_t)NN * 4);  // 30 KB

    gnode_weights<<<11, 256, 0, stream>>>(
        ode_w1, ode_b1, ode_w2, ode_b2,
        enc_n_w2, enc_e_w2, dec_n_w1, dec_n_w2, node_out_w, wg);

    gnode_main<<<GRID, 256, 0, stream>>>(
        nodes, edges, g,
        enc_n_w1, enc_n_b1, enc_n_b2,
        enc_e_w1, enc_e_b1, enc_e_b2,
        node_out_b, dec_n_b1, dec_n_b2, dec_n_w3, dec_n_b3,
        wg, out, npos);

    gnode_edges<<<(EE + 255) / 256, 256, 0, stream>>>(npos, out, g);
}